// Round 18
// baseline (449.626 us; speedup 1.0000x reference)
//
#include <hip/hip_runtime.h>

namespace {
constexpr int TT = 128;

__device__ __forceinline__ float rdlane(float v, int l) {
  return __int_as_float(__builtin_amdgcn_readlane(__float_as_int(v), l));
}

__device__ __forceinline__ void bsync() {
  // 256-thread barrier WITHOUT vmcnt drain: global prefetches stay in flight.
  asm volatile("s_waitcnt lgkmcnt(0)" ::: "memory");
  __builtin_amdgcn_s_barrier();
  asm volatile("" ::: "memory");
  __builtin_amdgcn_sched_barrier(0);
}

// Grid = B/2 (256 blocks -> ~1 block/CU). Each block solves its TWO chains
// sequentially: per-step phases run with no co-resident block contention.
__global__ __launch_bounds__(256)
void lqr_kernel(const float* __restrict__ Qg, const float* __restrict__ pg,
                const float* __restrict__ Fg, const float* __restrict__ cg,
                const float* __restrict__ x0g, float* __restrict__ out)
{
  // Quad-XOR-swizzled tiles: element (row, n) at row*S + ((n>>2 ^ ((row>>2)&3))<<2) + (n&3)
  __shared__ __align__(16) float VT[16][20];     // plain; V rows (symmetric)
  __shared__ __align__(16) float vv[16];
  __shared__ __align__(16) float FTxd[2][25][20];// swz; rows 0..23 = F cols, 24 = c
  __shared__ __align__(16) float WTx[25][20];    // swz; rows = W^T cols, 24 = z
  __shared__ __align__(16) float QhT[25][36];    // swz; rows = Qh cols, 24 = qh
  __shared__ __align__(16) float KsT[TT][8][16]; // KsT[t][c][i] = K[c][i]
  __shared__ __align__(16) float ksv[TT][8];

  const int tid  = threadIdx.x;
  const int lane = tid & 63;
  const int wv   = tid >> 6;

  const int jl = tid & 31;   // per-lane column index (valid <25 / <24)
  const int g  = tid >> 5;   // 0..7, uniform per half-wave

  // ---- F/c staging: unit u = tid < 100 (waves 0-1 only): j = u>>2, k = u&3
  const int  fj   = tid >> 2, fk = tid & 3;
  const bool fact = (tid < 100);
  const int  fsw  = (fj < 24) ? ((fj >> 2) & 3) : 2;

  for (int cc = 0; cc < 2; ++cc) {
    const int b = blockIdx.x * 2 + cc;
    const size_t bt0 = (size_t)b * TT;

    // zero ALL of VT (320 floats) + vv
    for (int e = tid; e < 320; e += 256) (&VT[0][0])[e] = 0.f;
    if (tid < 16) vv[tid] = 0.f;

    // x0 prefetch (wave 0 only; consumed 128 steps later in the rollout)
    float xv = 0.f;
    if (wv == 0 && lane < 16) xv = x0g[(size_t)b * 16 + lane];

    float Fr4[4] = {0.f, 0.f, 0.f, 0.f};

    auto loadF = [&](int t) {
      if (fact) {
        if (fj < 24) {
          const float* Fs = Fg + (bt0 + t) * 384 + fj;
          #pragma unroll
          for (int m = 0; m < 4; ++m) Fr4[m] = Fs[(4 * fk + m) * 24];
        } else {
          const float* cs = cg + (bt0 + t) * 16 + 4 * fk;
          #pragma unroll
          for (int m = 0; m < 4; ++m) Fr4[m] = cs[m];
        }
      }
    };
    auto commitF = [&](int buf) {
      if (fact) {
        float* dst = &FTxd[buf][fj][(fk ^ fsw) << 2];
        *(float4*)dst = make_float4(Fr4[0], Fr4[1], Fr4[2], Fr4[3]);
      }
    };

    float qreg[3] = {0.f, 0.f, 0.f}, qreg3 = 0.f;
    auto loadQ = [&](int t) {
      if (jl < 24) {
        const float* Qs = Qg + (bt0 + t) * 576;
        #pragma unroll
        for (int r = 0; r < 3; ++r) qreg[r] = Qs[(3 * g + r) * 24 + jl]; // Q sym
        if (g == 7) qreg3 = pg[(bt0 + t) * 24 + jl];
      }
    };

    // ---- prologue ----
    loadF(TT - 1);
    loadQ(TT - 1);
    commitF(1);
    loadF(TT - 2);
    bsync();

    // ===================== backward Riccati =====================
    for (int t = TT - 1; t >= 0; --t) {
      const float* Fb = &FTxd[t & 1][0][0];

      // Phase A: WTx[j][m] = sum_n V[m][n] * F[n][j]  (+v for j==24 -> z)
      float fr[16];
      if (jl < 25) {
        const int sj = (jl >> 2) & 3;
        const float* fb = Fb + jl * 20;
        #pragma unroll
        for (int q = 0; q < 4; ++q) {
          float4 v4 = *(const float4*)(fb + ((q ^ sj) << 2));
          fr[4*q+0] = v4.x; fr[4*q+1] = v4.y; fr[4*q+2] = v4.z; fr[4*q+3] = v4.w;
        }
        const int m0 = 2 * g, m1 = m0 + 1;
        float acc0 = (jl == 24) ? vv[m0] : 0.f;
        float acc1 = (jl == 24) ? vv[m1] : 0.f;
        #pragma unroll
        for (int q = 0; q < 4; ++q) {
          float4 a0 = *(const float4*)(&VT[m0][4*q]);   // broadcast per half-wave
          float4 a1 = *(const float4*)(&VT[m1][4*q]);
          acc0 = fmaf(a0.x, fr[4*q+0], acc0); acc0 = fmaf(a0.y, fr[4*q+1], acc0);
          acc0 = fmaf(a0.z, fr[4*q+2], acc0); acc0 = fmaf(a0.w, fr[4*q+3], acc0);
          acc1 = fmaf(a1.x, fr[4*q+0], acc1); acc1 = fmaf(a1.y, fr[4*q+1], acc1);
          acc1 = fmaf(a1.z, fr[4*q+2], acc1); acc1 = fmaf(a1.w, fr[4*q+3], acc1);
        }
        float* wb = &WTx[0][0] + jl * 20;
        *(float2*)(wb + ((((g >> 1) ^ sj) << 2) + (m0 & 3))) = make_float2(acc0, acc1);
      }
      bsync();

      // Phase B: QhT[c][i] = Qsrc + sum_m F[m][i] * W[m][c]   (i = jl)
      if (jl < 24) {
        #pragma unroll
        for (int r = 0; r < 3; ++r) {
          const int c = 3 * g + r;
          const int sc = (c >> 2) & 3;
          const float* wb = &WTx[0][0] + c * 20;   // broadcast per half-wave
          float acc = qreg[r];
          #pragma unroll
          for (int q = 0; q < 4; ++q) {
            float4 w4 = *(const float4*)(wb + ((q ^ sc) << 2));
            acc = fmaf(w4.x, fr[4*q+0], acc); acc = fmaf(w4.y, fr[4*q+1], acc);
            acc = fmaf(w4.z, fr[4*q+2], acc); acc = fmaf(w4.w, fr[4*q+3], acc);
          }
          float* qb = &QhT[0][0] + c * 36;
          qb[(((jl >> 2) ^ sc) << 2) + (jl & 3)] = acc;
        }
        if (g == 7) {                               // qh row (c==24), s=2
          const float* wb = &WTx[0][0] + 24 * 20;
          float acc = qreg3;
          #pragma unroll
          for (int q = 0; q < 4; ++q) {
            float4 w4 = *(const float4*)(wb + ((q ^ 2) << 2));
            acc = fmaf(w4.x, fr[4*q+0], acc); acc = fmaf(w4.y, fr[4*q+1], acc);
            acc = fmaf(w4.z, fr[4*q+2], acc); acc = fmaf(w4.w, fr[4*q+3], acc);
          }
          float* qb = &QhT[0][0] + 24 * 36;
          qb[(((jl >> 2) ^ 2) << 2) + (jl & 3)] = acc;
        }
      }
      if (t > 0) loadQ(t - 1);
      bsync();

      // GJ + gains + V-update on wave 2+(t&1); waves != GJ commit next F tile.
      if (wv == 2 + (t & 1)) {
        __builtin_amdgcn_s_setprio(1);
        // elim lanes: 0..7 = Quu cols, 8..23 = Qux cols (x-col j at lane 8+j),
        // 24 = qu. After 8 pivots: lane 8+j: a_ = X[:,j]; lane 24: xq.
        const int cl = (lane < 25) ? lane : 0;
        const int row = (cl < 8) ? (16 + cl) : ((cl < 24) ? (cl - 8) : 24);
        const int s = (row >> 2) & 3;
        const float* base = &QhT[0][0] + row * 36;
        float a_[8];
        {
          float4 x0v = *(const float4*)(base + ((4 ^ s) << 2));
          float4 x1v = *(const float4*)(base + ((5 ^ s) << 2));
          a_[0]=x0v.x; a_[1]=x0v.y; a_[2]=x0v.z; a_[3]=x0v.w;
          a_[4]=x1v.x; a_[5]=x1v.y; a_[6]=x1v.z; a_[7]=x1v.w;
        }
        // hoisted V-update reads: latency hides under the elim chain
        const int jv = lane & 31;
        const int ih = lane >> 5;
        const int row2 = (jv < 16) ? jv : 24;
        const int s3 = (row2 >> 2) & 3;
        const float* b2 = &QhT[0][0] + row2 * 36;
        const int q0 = 2 * ih, q1 = q0 + 1;
        float4 A0 = *(const float4*)(b2 + ((q0 ^ s3) << 2));
        float4 A1 = *(const float4*)(b2 + ((q1 ^ s3) << 2));
        float4 Bq0[8], Bq1[8];
        #pragma unroll
        for (int c = 0; c < 8; ++c) {
          const int s2 = ((16 + c) >> 2) & 3;        // compile-time 0 or 1
          const float* qb = &QhT[0][0] + (16 + c) * 36;
          Bq0[c] = *(const float4*)(qb + ((q0 ^ s2) << 2));
          Bq1[c] = *(const float4*)(qb + ((q1 ^ s2) << 2));
        }
        // 8-pivot elimination (unchanged arithmetic)
        #pragma unroll
        for (int pp = 0; pp < 8; ++pp) {
          float f_[8];
          f_[0] = rdlane(a_[0], pp); f_[1] = rdlane(a_[1], pp);
          f_[2] = rdlane(a_[2], pp); f_[3] = rdlane(a_[3], pp);
          f_[4] = rdlane(a_[4], pp); f_[5] = rdlane(a_[5], pp);
          f_[6] = rdlane(a_[6], pp); f_[7] = rdlane(a_[7], pp);
          // Quu >= I (pivot >= ~1): raw v_rcp (~2^-22 rel err) is plenty.
          float d = __builtin_amdgcn_rcpf(f_[pp]);
          a_[pp] *= d;
          #pragma unroll
          for (int r = 0; r < 8; ++r)
            if (r != pp) a_[r] = fmaf(-f_[r], a_[pp], a_[r]);
        }
        // gains, transposed store: KsT[t][c][j] = -X[c][j]; ksv = -xq
        if (lane >= 8 && lane < 24) {
          const int j = lane - 8;
          #pragma unroll
          for (int c = 0; c < 8; ++c) KsT[t][c][j] = -a_[c];
        } else if (lane == 24) {
          float4* kp = (float4*)&ksv[t][0];
          kp[0] = make_float4(-a_[0], -a_[1], -a_[2], -a_[3]);
          kp[1] = make_float4(-a_[4], -a_[5], -a_[6], -a_[7]);
        }
        // V-update spread over 64 lanes: lane (jv, ih) -> Vn[8ih..8ih+7][jv]
        const int sl = (jv < 16) ? (8 + jv) : 24;
        float xj[8];
        #pragma unroll
        for (int c = 0; c < 8; ++c)
          xj[c] = __int_as_float(
              __builtin_amdgcn_ds_bpermute(sl * 4, __float_as_int(a_[c])));
        if (jv < 16 || jv == 24) {
          float acc[8];
          acc[0]=A0.x; acc[1]=A0.y; acc[2]=A0.z; acc[3]=A0.w;
          acc[4]=A1.x; acc[5]=A1.y; acc[6]=A1.z; acc[7]=A1.w;
          #pragma unroll
          for (int c = 0; c < 8; ++c) {
            const float xc = xj[c];
            acc[0] = fmaf(-xc, Bq0[c].x, acc[0]); acc[1] = fmaf(-xc, Bq0[c].y, acc[1]);
            acc[2] = fmaf(-xc, Bq0[c].z, acc[2]); acc[3] = fmaf(-xc, Bq0[c].w, acc[3]);
            acc[4] = fmaf(-xc, Bq1[c].x, acc[4]); acc[5] = fmaf(-xc, Bq1[c].y, acc[5]);
            acc[6] = fmaf(-xc, Bq1[c].z, acc[6]); acc[7] = fmaf(-xc, Bq1[c].w, acc[7]);
          }
          float4* vp = (jv < 16) ? (float4*)&VT[jv][8 * ih] : (float4*)&vv[8 * ih];
          vp[0] = make_float4(acc[0], acc[1], acc[2], acc[3]);
          vp[1] = make_float4(acc[4], acc[5], acc[6], acc[7]);
        }
        __builtin_amdgcn_s_setprio(0);
      } else {
        // staging threads live ONLY in waves 0-1 (fact = tid<100), never GJ.
        if (t > 0) commitF((t - 1) & 1);
        if (t > 1) loadF(t - 2);
      }
      bsync();
    }

    // ================= forward rollout (wave 0 only) =================
    if (wv == 0) {
      float xs_[16];
      #pragma unroll
      for (int i = 0; i < 16; ++i) xs_[i] = rdlane(xv, i);

      float FA[24], FB[24];
      float cA = 0.f, cB = 0.f;
      float KA[16], KB[16], kA = 0.f, kB = 0.f;

      auto loadFw = [&](int t, float (&Fr)[24], float& cr) {
        if (lane < 16) {
          const float* src = Fg + (bt0 + t) * 384 + lane * 24;
          #pragma unroll
          for (int r = 0; r < 6; ++r) {
            float4 f4v = ((const float4*)src)[r];
            Fr[4*r+0] = f4v.x; Fr[4*r+1] = f4v.y; Fr[4*r+2] = f4v.z; Fr[4*r+3] = f4v.w;
          }
          cr = cg[(bt0 + t) * 16 + lane];
        }
      };
      auto loadK = [&](int t, float (&K)[16], float& kk) {
        if (lane < 8) {
          const float4* kp = (const float4*)&KsT[t][lane][0];
          float4 k0 = kp[0], k1 = kp[1], k2 = kp[2], k3 = kp[3];
          K[0]=k0.x;  K[1]=k0.y;  K[2]=k0.z;  K[3]=k0.w;
          K[4]=k1.x;  K[5]=k1.y;  K[6]=k1.z;  K[7]=k1.w;
          K[8]=k2.x;  K[9]=k2.y;  K[10]=k2.z; K[11]=k2.w;
          K[12]=k3.x; K[13]=k3.y; K[14]=k3.z; K[15]=k3.w;
          kk = ksv[t][lane];
        }
      };

      auto fstep = [&](int t, const float (&Fr)[24], float cr,
                       const float (&K)[16], float kk) {
        float uv = 0.f;
        if (lane < 8) {
          float u0 = kk, u1 = 0.f;
          #pragma unroll
          for (int i = 0; i < 16; i += 2) {
            u0 = fmaf(K[i],     xs_[i],     u0);
            u1 = fmaf(K[i + 1], xs_[i + 1], u1);
          }
          uv = u0 + u1;
        }
        float us[8];
        #pragma unroll
        for (int c = 0; c < 8; ++c) us[c] = rdlane(uv, c);
        float* o = out + (bt0 + t) * 24;
        if (lane < 16) o[lane] = xv;
        if (lane < 8)  o[16 + lane] = uv;
        float x0a = cr, x1a = 0.f;
        #pragma unroll
        for (int j2 = 0; j2 < 16; j2 += 2) {
          x0a = fmaf(Fr[j2],     xs_[j2],     x0a);
          x1a = fmaf(Fr[j2 + 1], xs_[j2 + 1], x1a);
        }
        #pragma unroll
        for (int c = 0; c < 8; c += 2) {
          x0a = fmaf(Fr[16 + c],     us[c],     x0a);
          x1a = fmaf(Fr[16 + c + 1], us[c + 1], x1a);
        }
        xv = x0a + x1a;
        #pragma unroll
        for (int i = 0; i < 16; ++i) xs_[i] = rdlane(xv, i);
      };

      loadFw(0, FA, cA); loadK(0, KA, kA);
      for (int t = 0; t < TT; t += 2) {
        if (t + 1 < TT) { loadFw(t + 1, FB, cB); loadK(t + 1, KB, kB); }
        fstep(t, FA, cA, KA, kA);
        if (t + 2 < TT) { loadFw(t + 2, FA, cA); loadK(t + 2, KA, kA); }
        fstep(t + 1, FB, cB, KB, kB);
      }
    }
    // all waves rejoin before reusing LDS (KsT/VT) for the next chain
    bsync();
  }
}
} // namespace

extern "C" void kernel_launch(void* const* d_in, const int* in_sizes, int n_in,
                              void* d_out, int out_size, void* d_ws, size_t ws_size,
                              hipStream_t stream)
{
  (void)n_in; (void)out_size; (void)d_ws; (void)ws_size;
  const float* Q  = (const float*)d_in[0];
  const float* p  = (const float*)d_in[1];
  const float* F  = (const float*)d_in[2];
  const float* c1 = (const float*)d_in[3];
  const float* x0 = (const float*)d_in[4];
  float* outp = (float*)d_out;

  const int B = in_sizes[4] / 16;   // 512 chains
  lqr_kernel<<<B / 2, 256, 0, stream>>>(Q, p, F, c1, x0, outp);
}

// Round 19
// 258.833 us; speedup vs baseline: 1.7371x; 1.7371x over previous
//
#include <hip/hip_runtime.h>

namespace {
constexpr int TT = 128;

__device__ __forceinline__ float rdlane(float v, int l) {
  return __int_as_float(__builtin_amdgcn_readlane(__float_as_int(v), l));
}

__device__ __forceinline__ void bsync() {
  // 256-thread barrier WITHOUT vmcnt drain: global prefetches stay in flight.
  asm volatile("s_waitcnt lgkmcnt(0)" ::: "memory");
  __builtin_amdgcn_s_barrier();
  asm volatile("" ::: "memory");
  __builtin_amdgcn_sched_barrier(0);
}

__global__ __launch_bounds__(256)
void lqr_kernel(const float* __restrict__ Qg, const float* __restrict__ pg,
                const float* __restrict__ Fg, const float* __restrict__ cg,
                const float* __restrict__ x0g, float* __restrict__ out)
{
  // Quad-XOR-swizzled tiles: element (row, n) at row*S + ((n>>2 ^ ((row>>2)&3))<<2) + (n&3)
  __shared__ __align__(16) float VT[16][20];     // plain; V columns (symmetric)
  __shared__ __align__(16) float vv[16];
  __shared__ __align__(16) float FTxd[2][25][20];// swz; rows 0..23 = F cols, 24 = c
  __shared__ __align__(16) float WTx[25][20];    // swz; rows = W^T cols, 24 = z
  __shared__ __align__(16) float QhT[25][36];    // swz; rows = Qh cols, 24 = qh
  __shared__ __align__(16) float KsT[TT][8][16]; // KsT[t][c][i] = K[c][i]
  __shared__ __align__(16) float ksv[TT][8];

  const int tid  = threadIdx.x;
  const int lane = tid & 63;
  const int wv   = tid >> 6;
  const int b    = blockIdx.x;
  const size_t bt0 = (size_t)b * TT;

  const int jl = tid & 31;   // per-lane column index (valid <25 / <24)
  const int g  = tid >> 5;   // 0..7, uniform per half-wave

  // zero ALL of VT (320 floats) + vv
  for (int e = tid; e < 320; e += 256) (&VT[0][0])[e] = 0.f;
  if (tid < 16) vv[tid] = 0.f;

  // ---- F/c staging: unit u = tid < 100 (waves 0-1 only): j = u>>2, k = u&3
  const int  fj   = tid >> 2, fk = tid & 3;
  const bool fact = (tid < 100);
  const int  fsw  = (fj < 24) ? ((fj >> 2) & 3) : 2;
  float Fr4[4] = {0.f, 0.f, 0.f, 0.f};

  auto loadF = [&](int t) {
    if (fact) {
      if (fj < 24) {
        const float* Fs = Fg + (bt0 + t) * 384 + fj;
        #pragma unroll
        for (int m = 0; m < 4; ++m) Fr4[m] = Fs[(4 * fk + m) * 24];
      } else {
        const float* cs = cg + (bt0 + t) * 16 + 4 * fk;
        #pragma unroll
        for (int m = 0; m < 4; ++m) Fr4[m] = cs[m];
      }
    }
  };
  auto commitF = [&](int buf) {
    if (fact) {
      float* dst = &FTxd[buf][fj][(fk ^ fsw) << 2];
      *(float4*)dst = make_float4(Fr4[0], Fr4[1], Fr4[2], Fr4[3]);
    }
  };

  float qreg[3] = {0.f, 0.f, 0.f}, qreg3 = 0.f;
  auto loadQ = [&](int t) {
    if (jl < 24) {
      const float* Qs = Qg + (bt0 + t) * 576;
      #pragma unroll
      for (int r = 0; r < 3; ++r) qreg[r] = Qs[(3 * g + r) * 24 + jl]; // Q sym
      if (g == 7) qreg3 = pg[(bt0 + t) * 24 + jl];
    }
  };

  // ---- prologue ----
  loadF(TT - 1);
  loadQ(TT - 1);
  commitF(1);
  loadF(TT - 2);
  bsync();

  // ===================== backward Riccati =====================
  for (int t = TT - 1; t >= 0; --t) {
    const float* Fb = &FTxd[t & 1][0][0];

    // Phase A: WTx[j][m] = sum_n V[m][n] * F[n][j]  (+v for j==24 -> z)
    float fr[16];
    if (jl < 25) {
      const int sj = (jl >> 2) & 3;
      const float* fb = Fb + jl * 20;
      #pragma unroll
      for (int q = 0; q < 4; ++q) {
        float4 v4 = *(const float4*)(fb + ((q ^ sj) << 2));
        fr[4*q+0] = v4.x; fr[4*q+1] = v4.y; fr[4*q+2] = v4.z; fr[4*q+3] = v4.w;
      }
      const int m0 = 2 * g, m1 = m0 + 1;
      float acc0 = (jl == 24) ? vv[m0] : 0.f;
      float acc1 = (jl == 24) ? vv[m1] : 0.f;
      #pragma unroll
      for (int q = 0; q < 4; ++q) {
        float4 a0 = *(const float4*)(&VT[m0][4*q]);   // broadcast per half-wave
        float4 a1 = *(const float4*)(&VT[m1][4*q]);
        acc0 = fmaf(a0.x, fr[4*q+0], acc0); acc0 = fmaf(a0.y, fr[4*q+1], acc0);
        acc0 = fmaf(a0.z, fr[4*q+2], acc0); acc0 = fmaf(a0.w, fr[4*q+3], acc0);
        acc1 = fmaf(a1.x, fr[4*q+0], acc1); acc1 = fmaf(a1.y, fr[4*q+1], acc1);
        acc1 = fmaf(a1.z, fr[4*q+2], acc1); acc1 = fmaf(a1.w, fr[4*q+3], acc1);
      }
      float* wb = &WTx[0][0] + jl * 20;
      *(float2*)(wb + ((((g >> 1) ^ sj) << 2) + (m0 & 3))) = make_float2(acc0, acc1);
    }
    bsync();

    // Phase B: QhT[c][i] = Qsrc + sum_m F[m][i] * W[m][c]   (i = jl)
    if (jl < 24) {
      #pragma unroll
      for (int r = 0; r < 3; ++r) {
        const int c = 3 * g + r;
        const int sc = (c >> 2) & 3;
        const float* wb = &WTx[0][0] + c * 20;   // broadcast per half-wave
        float acc = qreg[r];
        #pragma unroll
        for (int q = 0; q < 4; ++q) {
          float4 w4 = *(const float4*)(wb + ((q ^ sc) << 2));
          acc = fmaf(w4.x, fr[4*q+0], acc); acc = fmaf(w4.y, fr[4*q+1], acc);
          acc = fmaf(w4.z, fr[4*q+2], acc); acc = fmaf(w4.w, fr[4*q+3], acc);
        }
        float* qb = &QhT[0][0] + c * 36;
        qb[(((jl >> 2) ^ sc) << 2) + (jl & 3)] = acc;
      }
      if (g == 7) {                               // qh row (c==24), s=2
        const float* wb = &WTx[0][0] + 24 * 20;
        float acc = qreg3;
        #pragma unroll
        for (int q = 0; q < 4; ++q) {
          float4 w4 = *(const float4*)(wb + ((q ^ 2) << 2));
          acc = fmaf(w4.x, fr[4*q+0], acc); acc = fmaf(w4.y, fr[4*q+1], acc);
          acc = fmaf(w4.z, fr[4*q+2], acc); acc = fmaf(w4.w, fr[4*q+3], acc);
        }
        float* qb = &QhT[0][0] + 24 * 36;
        qb[(((jl >> 2) ^ 2) << 2) + (jl & 3)] = acc;
      }
    }
    if (t > 0) loadQ(t - 1);
    bsync();

    // GJ + gains + V-update on wave 2+(t&1); waves != GJ commit next F tile.
    // Lane layout: lanes 0..7 hold Quu cols, 8..23 hold Qux cols (x-col j at
    // lane 8+j), 24 holds qu. After 8 pivots lane 8+j: a_ = X[:,j]; lane 24: xq.
    if (wv == 2 + (t & 1)) {
      __builtin_amdgcn_s_setprio(1);
      const int cl = (lane < 25) ? lane : 0;
      const int row = (cl < 8) ? (16 + cl) : ((cl < 24) ? (cl - 8) : 24);
      const int s = (row >> 2) & 3;
      const float* base = &QhT[0][0] + row * 36;
      float a_[8];
      {
        float4 x0v = *(const float4*)(base + ((4 ^ s) << 2));
        float4 x1v = *(const float4*)(base + ((5 ^ s) << 2));
        a_[0]=x0v.x; a_[1]=x0v.y; a_[2]=x0v.z; a_[3]=x0v.w;
        a_[4]=x1v.x; a_[5]=x1v.y; a_[6]=x1v.z; a_[7]=x1v.w;
      }
      // ---- hoisted V-update reads: latency hides under the elim chain ----
      const int jv = lane & 31;
      const int ih = lane >> 5;
      const int row2 = (jv < 16) ? jv : 24;
      const int s3 = (row2 >> 2) & 3;
      const float* b2 = &QhT[0][0] + row2 * 36;
      const int q0 = 2 * ih, q1 = q0 + 1;
      float4 A0 = *(const float4*)(b2 + ((q0 ^ s3) << 2));
      float4 A1 = *(const float4*)(b2 + ((q1 ^ s3) << 2));
      float4 Bq0[8], Bq1[8];
      #pragma unroll
      for (int c = 0; c < 8; ++c) {
        const int s2 = ((16 + c) >> 2) & 3;         // compile-time 0 or 1
        const float* qb = &QhT[0][0] + (16 + c) * 36;
        Bq0[c] = *(const float4*)(qb + ((q0 ^ s2) << 2));
        Bq1[c] = *(const float4*)(qb + ((q1 ^ s2) << 2));
      }
      // ---- 8-pivot elimination (unchanged arithmetic) ----
      #pragma unroll
      for (int pp = 0; pp < 8; ++pp) {
        float f_[8];
        f_[0] = rdlane(a_[0], pp); f_[1] = rdlane(a_[1], pp);
        f_[2] = rdlane(a_[2], pp); f_[3] = rdlane(a_[3], pp);
        f_[4] = rdlane(a_[4], pp); f_[5] = rdlane(a_[5], pp);
        f_[6] = rdlane(a_[6], pp); f_[7] = rdlane(a_[7], pp);
        // Quu >= I (pivot >= ~1): raw v_rcp (~2^-22 rel err) is plenty.
        float d = __builtin_amdgcn_rcpf(f_[pp]);
        a_[pp] *= d;
        #pragma unroll
        for (int r = 0; r < 8; ++r)
          if (r != pp) a_[r] = fmaf(-f_[r], a_[pp], a_[r]);
      }
      // gains, transposed store: KsT[t][c][j] = K[c][j] = -X[c][j]
      if (lane >= 8 && lane < 24) {
        const int j = lane - 8;
        #pragma unroll
        for (int c = 0; c < 8; ++c) KsT[t][c][j] = -a_[c];
      } else if (lane == 24) {
        float4* kp = (float4*)&ksv[t][0];
        kp[0] = make_float4(-a_[0], -a_[1], -a_[2], -a_[3]);
        kp[1] = make_float4(-a_[4], -a_[5], -a_[6], -a_[7]);
      }
      // V-update spread over 64 lanes: lane (jv, ih) computes Vn[8ih..8ih+7][jv]
      // (jv==24 -> vn). X[:,jv] pulled from lane 8+jv (or 24) via ds_bpermute.
      const int sl = (jv < 16) ? (8 + jv) : 24;
      float xj[8];
      #pragma unroll
      for (int c = 0; c < 8; ++c)
        xj[c] = __int_as_float(
            __builtin_amdgcn_ds_bpermute(sl * 4, __float_as_int(a_[c])));
      if (jv < 16 || jv == 24) {
        float acc[8];
        acc[0]=A0.x; acc[1]=A0.y; acc[2]=A0.z; acc[3]=A0.w;
        acc[4]=A1.x; acc[5]=A1.y; acc[6]=A1.z; acc[7]=A1.w;
        #pragma unroll
        for (int c = 0; c < 8; ++c) {
          const float xc = xj[c];
          acc[0] = fmaf(-xc, Bq0[c].x, acc[0]); acc[1] = fmaf(-xc, Bq0[c].y, acc[1]);
          acc[2] = fmaf(-xc, Bq0[c].z, acc[2]); acc[3] = fmaf(-xc, Bq0[c].w, acc[3]);
          acc[4] = fmaf(-xc, Bq1[c].x, acc[4]); acc[5] = fmaf(-xc, Bq1[c].y, acc[5]);
          acc[6] = fmaf(-xc, Bq1[c].z, acc[6]); acc[7] = fmaf(-xc, Bq1[c].w, acc[7]);
        }
        float4* vp = (jv < 16) ? (float4*)&VT[jv][8 * ih] : (float4*)&vv[8 * ih];
        vp[0] = make_float4(acc[0], acc[1], acc[2], acc[3]);
        vp[1] = make_float4(acc[4], acc[5], acc[6], acc[7]);
      }
      __builtin_amdgcn_s_setprio(0);
    } else {
      // staging threads live ONLY in waves 0-1 (fact = tid<100), never GJ.
      if (t > 0) commitF((t - 1) & 1);
      if (t > 1) loadF(t - 2);
    }
    bsync();
  }

  // ===================== forward rollout (wave 0 only) =====================
  if (wv != 0) return;

  float xv = (lane < 16) ? x0g[(size_t)b * 16 + lane] : 0.f;
  float xs_[16];
  #pragma unroll
  for (int i = 0; i < 16; ++i) xs_[i] = rdlane(xv, i);

  float FA[24], FB[24];
  float cA = 0.f, cB = 0.f;
  float KA[16], KB[16], kA = 0.f, kB = 0.f;

  auto loadFw = [&](int t, float (&Fr)[24], float& cr) {
    if (lane < 16) {
      const float* src = Fg + (bt0 + t) * 384 + lane * 24;
      #pragma unroll
      for (int r = 0; r < 6; ++r) {
        float4 f4v = ((const float4*)src)[r];
        Fr[4*r+0] = f4v.x; Fr[4*r+1] = f4v.y; Fr[4*r+2] = f4v.z; Fr[4*r+3] = f4v.w;
      }
      cr = cg[(bt0 + t) * 16 + lane];
    }
  };
  auto loadK = [&](int t, float (&K)[16], float& kk) {
    if (lane < 8) {
      const float4* kp = (const float4*)&KsT[t][lane][0];
      float4 k0 = kp[0], k1 = kp[1], k2 = kp[2], k3 = kp[3];
      K[0]=k0.x;  K[1]=k0.y;  K[2]=k0.z;  K[3]=k0.w;
      K[4]=k1.x;  K[5]=k1.y;  K[6]=k1.z;  K[7]=k1.w;
      K[8]=k2.x;  K[9]=k2.y;  K[10]=k2.z; K[11]=k2.w;
      K[12]=k3.x; K[13]=k3.y; K[14]=k3.z; K[15]=k3.w;
      kk = ksv[t][lane];
    }
  };

  auto fstep = [&](int t, const float (&Fr)[24], float cr,
                   const float (&K)[16], float kk) {
    float uv = 0.f;
    if (lane < 8) {
      float u0 = kk, u1 = 0.f;
      #pragma unroll
      for (int i = 0; i < 16; i += 2) {
        u0 = fmaf(K[i],     xs_[i],     u0);
        u1 = fmaf(K[i + 1], xs_[i + 1], u1);
      }
      uv = u0 + u1;
    }
    float us[8];
    #pragma unroll
    for (int c = 0; c < 8; ++c) us[c] = rdlane(uv, c);
    float* o = out + (bt0 + t) * 24;
    if (lane < 16) o[lane] = xv;
    if (lane < 8)  o[16 + lane] = uv;
    float x0a = cr, x1a = 0.f;
    #pragma unroll
    for (int j2 = 0; j2 < 16; j2 += 2) {
      x0a = fmaf(Fr[j2],     xs_[j2],     x0a);
      x1a = fmaf(Fr[j2 + 1], xs_[j2 + 1], x1a);
    }
    #pragma unroll
    for (int c = 0; c < 8; c += 2) {
      x0a = fmaf(Fr[16 + c],     us[c],     x0a);
      x1a = fmaf(Fr[16 + c + 1], us[c + 1], x1a);
    }
    xv = x0a + x1a;
    #pragma unroll
    for (int i = 0; i < 16; ++i) xs_[i] = rdlane(xv, i);
  };

  loadFw(0, FA, cA); loadK(0, KA, kA);
  for (int t = 0; t < TT; t += 2) {
    if (t + 1 < TT) { loadFw(t + 1, FB, cB); loadK(t + 1, KB, kB); }
    fstep(t, FA, cA, KA, kA);
    if (t + 2 < TT) { loadFw(t + 2, FA, cA); loadK(t + 2, KA, kA); }
    fstep(t + 1, FB, cB, KB, kB);
  }
}
} // namespace

extern "C" void kernel_launch(void* const* d_in, const int* in_sizes, int n_in,
                              void* d_out, int out_size, void* d_ws, size_t ws_size,
                              hipStream_t stream)
{
  (void)n_in; (void)out_size; (void)d_ws; (void)ws_size;
  const float* Q  = (const float*)d_in[0];
  const float* p  = (const float*)d_in[1];
  const float* F  = (const float*)d_in[2];
  const float* c1 = (const float*)d_in[3];
  const float* x0 = (const float*)d_in[4];
  float* outp = (float*)d_out;

  const int B = in_sizes[4] / 16;   // 512
  lqr_kernel<<<B, 256, 0, stream>>>(Q, p, F, c1, x0, outp);
}